// Round 2
// baseline (754.688 us; speedup 1.0000x reference)
//
#include <hip/hip_runtime.h>
#include <math.h>

#define BB 32
#define SS 4096
#define HH 1024
#define FF 1024
#define NCHUNK 32
#define SCHUNK (SS / NCHUNK)   /* 128 rows per chunk, 32 per wave */
#define PSTRIDE 1028           /* floats per partial record (16B-aligned stride) */

// ---------------- kernel 1: query = fv @ W_q + b_q ----------------
__global__ __launch_bounds__(256) void query_gemm(
        const float* __restrict__ fv,   // [B, F]
        const float* __restrict__ W,    // [F, H]
        const float* __restrict__ bq,   // [H]
        float* __restrict__ query) {    // [B, H]
    __shared__ float sfv[256];
    const int tid = threadIdx.x;
    const int h = blockIdx.x * 256 + tid;
    const int b = blockIdx.y;
    float acc = bq[h];
    for (int f0 = 0; f0 < FF; f0 += 256) {
        __syncthreads();
        sfv[tid] = fv[b * FF + f0 + tid];
        __syncthreads();
        #pragma unroll 8
        for (int j = 0; j < 256; ++j) {
            acc = fmaf(sfv[j], W[(size_t)(f0 + j) * HH + h], acc);
        }
    }
    query[b * HH + h] = acc;
}

// ------- kernel 2: per-(batch, S-chunk) online-softmax partial -------
// Each block: 4 waves, each wave owns SCHUNK/4 rows (interleaved by 4).
// Lane i of every wave owns H-positions {k*256 + i*4 .. +3 : k=0..3}.
__global__ __launch_bounds__(256) void attn_partial(
        const float* __restrict__ hidden,   // [B, S, H]
        const float* __restrict__ query,    // [B, H]
        float* __restrict__ partials) {     // [B*NCHUNK, PSTRIDE]
    const int c   = blockIdx.x;
    const int b   = blockIdx.y;
    const int tid = threadIdx.x;
    const int wid  = tid >> 6;
    const int lane = tid & 63;

    // query fragment for this lane (same positions as the hv loads)
    float4 q[4];
    const float4* q4 = (const float4*)(query + (size_t)b * HH);
    #pragma unroll
    for (int k = 0; k < 4; ++k) q[k] = q4[k * 64 + lane];

    float m = -1e30f, l = 0.f;
    float4 acc[4];
    #pragma unroll
    for (int k = 0; k < 4; ++k) acc[k] = make_float4(0.f, 0.f, 0.f, 0.f);

    const float* hb = hidden + (size_t)b * SS * HH;

    for (int it = 0; it < SCHUNK / 4; ++it) {
        const int s = c * SCHUNK + it * 4 + wid;
        const float4* h4 = (const float4*)(hb + (size_t)s * HH);
        float4 hv[4];
        #pragma unroll
        for (int k = 0; k < 4; ++k) hv[k] = h4[k * 64 + lane];

        float p = 0.f;
        #pragma unroll
        for (int k = 0; k < 4; ++k) {
            p = fmaf(hv[k].x, q[k].x, p);
            p = fmaf(hv[k].y, q[k].y, p);
            p = fmaf(hv[k].z, q[k].z, p);
            p = fmaf(hv[k].w, q[k].w, p);
        }
        // wave-64 butterfly reduce -> all lanes hold score
        #pragma unroll
        for (int off = 1; off < 64; off <<= 1)
            p += __shfl_xor(p, off, 64);
        const float score = p;

        if (score > m) {               // wave-uniform branch
            const float scale = __expf(m - score);
            l *= scale;
            #pragma unroll
            for (int k = 0; k < 4; ++k) {
                acc[k].x *= scale; acc[k].y *= scale;
                acc[k].z *= scale; acc[k].w *= scale;
            }
            m = score;
        }
        const float w = __expf(score - m);
        l += w;
        #pragma unroll
        for (int k = 0; k < 4; ++k) {
            acc[k].x = fmaf(w, hv[k].x, acc[k].x);
            acc[k].y = fmaf(w, hv[k].y, acc[k].y);
            acc[k].z = fmaf(w, hv[k].z, acc[k].z);
            acc[k].w = fmaf(w, hv[k].w, acc[k].w);
        }
    }

    // ---- merge the 4 wave partials through LDS ----
    __shared__ float sm[4], sl[4];
    __shared__ float sacc[4][HH];
    #pragma unroll
    for (int k = 0; k < 4; ++k)
        *((float4*)&sacc[wid][k * 256 + lane * 4]) = acc[k];
    if (lane == 0) { sm[wid] = m; sl[wid] = l; }
    __syncthreads();

    const float M = fmaxf(fmaxf(sm[0], sm[1]), fmaxf(sm[2], sm[3]));
    const float e0 = __expf(sm[0] - M);
    const float e1 = __expf(sm[1] - M);
    const float e2 = __expf(sm[2] - M);
    const float e3 = __expf(sm[3] - M);
    const float L = sl[0]*e0 + sl[1]*e1 + sl[2]*e2 + sl[3]*e3;

    const float4 a0 = *(const float4*)&sacc[0][tid * 4];
    const float4 a1 = *(const float4*)&sacc[1][tid * 4];
    const float4 a2 = *(const float4*)&sacc[2][tid * 4];
    const float4 a3 = *(const float4*)&sacc[3][tid * 4];
    float4 o;
    o.x = a0.x*e0 + a1.x*e1 + a2.x*e2 + a3.x*e3;
    o.y = a0.y*e0 + a1.y*e1 + a2.y*e2 + a3.y*e3;
    o.z = a0.z*e0 + a1.z*e1 + a2.z*e2 + a3.z*e3;
    o.w = a0.w*e0 + a1.w*e1 + a2.w*e2 + a3.w*e3;

    float* pb = partials + (size_t)(b * NCHUNK + c) * PSTRIDE;
    *((float4*)&pb[tid * 4]) = o;
    if (tid == 0) { pb[HH] = M; pb[HH + 1] = L; }
}

// ------- kernel 3: merge NCHUNK partials per batch, normalize -------
__global__ __launch_bounds__(256) void attn_combine(
        const float* __restrict__ partials,
        float* __restrict__ out) {          // [B, H]
    const int b = blockIdx.x;
    const int tid = threadIdx.x;
    const float* pbase = partials + (size_t)b * NCHUNK * PSTRIDE;

    float M = -1e30f;
    #pragma unroll
    for (int c = 0; c < NCHUNK; ++c)
        M = fmaxf(M, pbase[(size_t)c * PSTRIDE + HH]);

    float e[NCHUNK];
    float L = 0.f;
    #pragma unroll
    for (int c = 0; c < NCHUNK; ++c) {
        e[c] = __expf(pbase[(size_t)c * PSTRIDE + HH] - M);
        L = fmaf(pbase[(size_t)c * PSTRIDE + HH + 1], e[c], L);
    }
    const float inv = 1.0f / L;

    float4 o = make_float4(0.f, 0.f, 0.f, 0.f);
    #pragma unroll
    for (int c = 0; c < NCHUNK; ++c) {
        const float4 a = *(const float4*)&pbase[(size_t)c * PSTRIDE + tid * 4];
        const float w = e[c];
        o.x = fmaf(a.x, w, o.x);
        o.y = fmaf(a.y, w, o.y);
        o.z = fmaf(a.z, w, o.z);
        o.w = fmaf(a.w, w, o.w);
    }
    o.x *= inv; o.y *= inv; o.z *= inv; o.w *= inv;
    *((float4*)&out[(size_t)b * HH + tid * 4]) = o;
}

// ---------------------------------------------------------------
extern "C" void kernel_launch(void* const* d_in, const int* in_sizes, int n_in,
                              void* d_out, int out_size, void* d_ws, size_t ws_size,
                              hipStream_t stream) {
    const float* fv     = (const float*)d_in[0];  // [B, F]
    const float* hidden = (const float*)d_in[1];  // [B, S, H]
    const float* W      = (const float*)d_in[2];  // [F, H]
    const float* bq     = (const float*)d_in[3];  // [H]
    float* out = (float*)d_out;                   // [B, H]

    float* query    = (float*)d_ws;                         // B*H floats
    float* partials = query + (size_t)BB * HH;              // B*NCHUNK*PSTRIDE floats

    query_gemm<<<dim3(HH / 256, BB), 256, 0, stream>>>(fv, W, bq, query);
    attn_partial<<<dim3(NCHUNK, BB), 256, 0, stream>>>(hidden, query, partials);
    attn_combine<<<BB, 256, 0, stream>>>(partials, out);
}